// Round 1
// baseline (101.468 us; speedup 1.0000x reference)
//
#include <hip/hip_runtime.h>

#define NUM_MOLECULES 262144
#define NUM_ATOMS     8388608
#define TABLE_SIZE    100
#define BLOCK         256
#define CPT           16                  // atoms per thread: four int4 of z + four of m

// Kernel 1: out[m] = energy_readout[m]  (d_out is poisoned 0xAA before every call)
__global__ void init_out_kernel(const float* __restrict__ energy,
                                float* __restrict__ out, int n4) {
    int i = blockIdx.x * blockDim.x + threadIdx.x;
    if (i < n4) {
        reinterpret_cast<float4*>(out)[i] =
            reinterpret_cast<const float4*>(energy)[i];
    }
}

// Kernel 2: per-thread parse of 16 sorted atoms + wave-level head-flagged
// segmented scan (Hillis-Steele over 64 lanes) -> ~1 atomicAdd per segment run.
// CPT=16 halves the per-byte scan/shfl/bookkeeping overhead vs the measured
// CPT=8 variant (R4 baseline: accum ~16 us vs ~13.5 us stripped floor).
__global__ void __launch_bounds__(BLOCK)
accum_kernel(const int* __restrict__ atomic_numbers,
             const int* __restrict__ mol_idx,
             const float* __restrict__ table,
             float* __restrict__ out) {
    __shared__ float tab[TABLE_SIZE];
    if (threadIdx.x < TABLE_SIZE) tab[threadIdx.x] = table[threadIdx.x];
    __syncthreads();

    const int tid = blockIdx.x * blockDim.x + threadIdx.x;
    const int4* zp = reinterpret_cast<const int4*>(atomic_numbers);
    const int4* mp = reinterpret_cast<const int4*>(mol_idx);

    int4 zz[4], mm[4];
#pragma unroll
    for (int k = 0; k < 4; ++k) {
        zz[k] = zp[4 * tid + k];
        mm[k] = mp[4 * tid + k];
    }

    int z_all[CPT], m_all[CPT];
#pragma unroll
    for (int k = 0; k < 4; ++k) {
        z_all[4 * k + 0] = zz[k].x; z_all[4 * k + 1] = zz[k].y;
        z_all[4 * k + 2] = zz[k].z; z_all[4 * k + 3] = zz[k].w;
        m_all[4 * k + 0] = mm[k].x; m_all[4 * k + 1] = mm[k].y;
        m_all[4 * k + 2] = mm[k].z; m_all[4 * k + 3] = mm[k].w;
    }

    float v_all[CPT];
#pragma unroll
    for (int j = 0; j < CPT; ++j) v_all[j] = tab[z_all[j]];

    // ---- local parse of 16 atoms into head run / interior runs / tail run ----
    int   curm = m_all[0];
    float run  = v_all[0];
    float head_sum = 0.0f;     // sum of leading run (valid iff nbound > 0)
    int   nbound = 0;          // number of molecule changes inside this thread
#pragma unroll
    for (int j = 1; j < CPT; ++j) {
        if (m_all[j] == curm) {
            run += v_all[j];
        } else {
            if (nbound == 0) head_sum = run;            // head run closes (may connect backward)
            else atomicAdd(out + curm, run);            // interior complete run
            ++nbound;
            curm = m_all[j];
            run  = v_all[j];
        }
    }
    const int   head_mol = m_all[0];
    const int   tail_mol = curm;       // == m_all[CPT-1]
    const float tail_sum = run;

    const int lane = threadIdx.x & 63;

    // ---- cross-lane connectivity ----
    const int prev_tail = __shfl_up(tail_mol, 1);
    const bool connect = (lane > 0) && (head_mol == prev_tail);
    // "open": incoming run flows through this whole lane into its tail
    const bool open = (nbound == 0) && connect;

    // ---- segmented inclusive scan of tail_sum, head flag = !open ----
    float c = tail_sum;
    int   f = open ? 0 : 1;
#pragma unroll
    for (int d = 1; d < 64; d <<= 1) {
        float cp = __shfl_up(c, d);
        int   fp = __shfl_up(f, d);
        if (lane >= d && !f) {
            c += cp;
            f |= fp;
        }
    }
    // c = sum of the open tail-run chain ending at this lane

    // ---- flush the incoming head run (boundary lanes close it) ----
    const float cin = __shfl_up(c, 1);   // chain total through lane-1 (valid iff connect)
    if (nbound > 0) {
        atomicAdd(out + head_mol, head_sum + (connect ? cin : 0.0f));
    }

    // ---- flush tail chains not absorbed by the next lane ----
    const int next_connect = __shfl_down((int)connect, 1);
    const bool chain_end = (lane == 63) || !next_connect;
    if (chain_end) {
        atomicAdd(out + tail_mol, c);
    }
}

extern "C" void kernel_launch(void* const* d_in, const int* in_sizes, int n_in,
                              void* d_out, int out_size, void* d_ws, size_t ws_size,
                              hipStream_t stream) {
    const float* energy_readout = (const float*)d_in[0];
    const int*   atomic_numbers = (const int*)d_in[1];
    const int*   mol_idx        = (const int*)d_in[2];
    const float* table          = (const float*)d_in[3];
    float* out = (float*)d_out;

    // Kernel 1: copy energy_readout -> out (float4)
    int n4 = NUM_MOLECULES / 4;                 // 65536
    int b1 = 256;
    int g1 = (n4 + b1 - 1) / b1;                // 256 blocks
    init_out_kernel<<<g1, b1, 0, stream>>>(energy_readout, out, n4);

    // Kernel 2: segmented accumulation, 2048 blocks x 256 threads, 16 atoms/thread
    int g2 = NUM_ATOMS / (BLOCK * CPT);         // 2048
    accum_kernel<<<g2, BLOCK, 0, stream>>>(atomic_numbers, mol_idx, table, out);
}